// Round 3
// baseline (1028.565 us; speedup 1.0000x reference)
//
#include <hip/hip_runtime.h>
#include <hip/hip_fp16.h>

#define DD 1024
#define LL 128
#define NSEG 64

typedef _Float16 half8  __attribute__((ext_vector_type(8)));
typedef float    floatx4 __attribute__((ext_vector_type(4)));
typedef float    f4v     __attribute__((ext_vector_type(4)));

// ---------------- prep: convert Wa|Wb -> f16 Wab [256][1024], zero seg buffers ----
__global__ __launch_bounds__(256)
void prep_kernel(const float* __restrict__ Wa, const float* __restrict__ Wb,
                 _Float16* __restrict__ Wab, unsigned* __restrict__ smaxu,
                 float* __restrict__ denom)
{
    int gid = blockIdx.x * 256 + threadIdx.x;
    if (gid < LL * DD)            Wab[gid] = (_Float16)Wa[gid];
    else if (gid < 2 * LL * DD)   Wab[gid] = (_Float16)Wb[gid - LL * DD];
    if (gid < NSEG)               smaxu[gid] = 0u;
    else if (gid < 2 * NSEG)      denom[gid - NSEG] = 0.0f;
}

// ---- fused, wave-standalone: each wave owns 32 rows; no LDS, no barriers ----
__global__ __launch_bounds__(256, 2)
void fused_main(const float* __restrict__ feat,
                const _Float16* __restrict__ Wab,
                const float* __restrict__ ba,
                const float* __restrict__ bb,
                const float* __restrict__ Wc,
                const float* __restrict__ bc,
                float* __restrict__ out_norm,
                float* __restrict__ score_raw)
{
    const int tid  = threadIdx.x;
    const int wave = tid >> 6;
    const int lane = tid & 63;
    const int llo  = lane & 15;     // feature row within 16-row tile (A-frag row)
    const int lhi  = lane >> 4;     // k-slice selector

    const long long row0 = ((long long)blockIdx.x * 4 + wave) * 32;
    const float* fbase = feat + (size_t)(row0 + llo) * DD + lhi * 8;

    // -------- Phase 1: stream tile once, per-row sum of squares --------
    float ss0 = 0.0f, ss1 = 0.0f;
    #pragma unroll 4
    for (int ks = 0; ks < 32; ++ks) {
        const float4* p0 = reinterpret_cast<const float4*>(fbase + ks * 32);
        const float4* p1 = reinterpret_cast<const float4*>(fbase + 16 * DD + ks * 32);
        float4 u = p0[0], v = p0[1];
        float4 x = p1[0], y = p1[1];
        ss0 += u.x*u.x + u.y*u.y + u.z*u.z + u.w*u.w
             + v.x*v.x + v.y*v.y + v.z*v.z + v.w*v.w;
        ss1 += x.x*x.x + x.y*x.y + x.z*x.z + x.w*x.w
             + y.x*y.x + y.y*y.y + y.z*y.z + y.w*y.w;
    }
    // reduce across the 4 lanes (lhi=0..3) sharing each row llo
    ss0 += __shfl_xor(ss0, 16); ss0 += __shfl_xor(ss0, 32);
    ss1 += __shfl_xor(ss1, 16); ss1 += __shfl_xor(ss1, 32);
    const float rinv0 = 1.0f / fmaxf(sqrtf(ss0), 1e-12f);
    const float rinv1 = 1.0f / fmaxf(sqrtf(ss1), 1e-12f);

    // -------- Phase 2: re-read (L2/L3-hot), write out_norm, MFMA dual GEMM --------
    floatx4 acc[2][16];
    #pragma unroll
    for (int rt = 0; rt < 2; ++rt)
        #pragma unroll
        for (int ct = 0; ct < 16; ++ct) acc[rt][ct] = (floatx4)0.0f;

    float* obase = out_norm + (size_t)(row0 + llo) * DD + lhi * 8;
    const _Float16* wbase = Wab + (size_t)llo * DD + lhi * 8;

    #pragma unroll 1
    for (int ks = 0; ks < 32; ++ks) {
        half8 af0, af1;
        {
            const float4* p0 = reinterpret_cast<const float4*>(fbase + ks * 32);
            const float4* p1 = reinterpret_cast<const float4*>(fbase + 16 * DD + ks * 32);
            float4 u = p0[0], v = p0[1];
            float4 x = p1[0], y = p1[1];

            f4v o;
            o[0]=u.x*rinv0; o[1]=u.y*rinv0; o[2]=u.z*rinv0; o[3]=u.w*rinv0;
            __builtin_nontemporal_store(o, reinterpret_cast<f4v*>(obase + ks * 32));
            o[0]=v.x*rinv0; o[1]=v.y*rinv0; o[2]=v.z*rinv0; o[3]=v.w*rinv0;
            __builtin_nontemporal_store(o, reinterpret_cast<f4v*>(obase + ks * 32 + 4));
            o[0]=x.x*rinv1; o[1]=x.y*rinv1; o[2]=x.z*rinv1; o[3]=x.w*rinv1;
            __builtin_nontemporal_store(o, reinterpret_cast<f4v*>(obase + 16 * DD + ks * 32));
            o[0]=y.x*rinv1; o[1]=y.y*rinv1; o[2]=y.z*rinv1; o[3]=y.w*rinv1;
            __builtin_nontemporal_store(o, reinterpret_cast<f4v*>(obase + 16 * DD + ks * 32 + 4));

            af0[0]=(_Float16)u.x; af0[1]=(_Float16)u.y; af0[2]=(_Float16)u.z; af0[3]=(_Float16)u.w;
            af0[4]=(_Float16)v.x; af0[5]=(_Float16)v.y; af0[6]=(_Float16)v.z; af0[7]=(_Float16)v.w;
            af1[0]=(_Float16)x.x; af1[1]=(_Float16)x.y; af1[2]=(_Float16)x.z; af1[3]=(_Float16)x.w;
            af1[4]=(_Float16)y.x; af1[5]=(_Float16)y.y; af1[6]=(_Float16)y.z; af1[7]=(_Float16)y.w;
        }
        const _Float16* wk = wbase + ks * 32;
        #pragma unroll
        for (int ct = 0; ct < 16; ++ct) {
            half8 bf = *reinterpret_cast<const half8*>(wk + (size_t)ct * 16 * DD);
            acc[0][ct] = __builtin_amdgcn_mfma_f32_16x16x32_f16(af0, bf, acc[0][ct], 0, 0, 0);
            acc[1][ct] = __builtin_amdgcn_mfma_f32_16x16x32_f16(af1, bf, acc[1][ct], 0, 0, 0);
        }
    }

    // -------- epilogue: sigmoid(a)*tanh(b) . Wc, reduce over 16 out-col lanes --------
    float bav[8], bbv[8], wcv[8];
    #pragma unroll
    for (int ct = 0; ct < 8; ++ct) {
        const int c = ct * 16 + llo;
        bav[ct] = ba[c]; bbv[ct] = bb[c]; wcv[ct] = Wc[c];
    }
    const float bcv = bc[0];

    #pragma unroll
    for (int rt = 0; rt < 2; ++rt) {
        float s[4] = {0.f, 0.f, 0.f, 0.f};
        #pragma unroll
        for (int ct = 0; ct < 8; ++ct)
            #pragma unroll
            for (int j = 0; j < 4; ++j) {
                const float av = 1.0f / (1.0f + expf(-(acc[rt][ct][j] + bav[ct])));
                const float bv = tanhf(acc[rt][ct + 8][j] + bbv[ct]);
                s[j] += av * bv * wcv[ct];
            }
        #pragma unroll
        for (int j = 0; j < 4; ++j) {
            s[j] += __shfl_xor(s[j], 1);
            s[j] += __shfl_xor(s[j], 2);
            s[j] += __shfl_xor(s[j], 4);
            s[j] += __shfl_xor(s[j], 8);
        }
        if (llo == 0) {
            #pragma unroll
            for (int j = 0; j < 4; ++j)
                score_raw[row0 + rt * 16 + lhi * 4 + j] = s[j] + bcv;
        }
    }
}

// ---------------- segment softmax (3 tiny passes over N floats) ----------------
__global__ __launch_bounds__(256)
void seg_max_kernel(const float* __restrict__ score, const int* __restrict__ batch,
                    unsigned* __restrict__ smaxu, int n)
{
    __shared__ unsigned sm[NSEG];
    const int t = threadIdx.x;
    if (t < NSEG) sm[t] = 0u;
    __syncthreads();
    const int stride = gridDim.x * blockDim.x;
    for (int i = blockIdx.x * blockDim.x + t; i < n; i += stride) {
        const unsigned b = __float_as_uint(score[i]);
        const unsigned m = (b & 0x80000000u) ? ~b : (b | 0x80000000u);
        atomicMax(&sm[batch[i]], m);
    }
    __syncthreads();
    if (t < NSEG) atomicMax(&smaxu[t], sm[t]);
}

__global__ __launch_bounds__(256)
void seg_exp_kernel(float* __restrict__ score_inout, const int* __restrict__ batch,
                    const unsigned* __restrict__ smaxu, float* __restrict__ denom, int n)
{
    __shared__ float sd[NSEG];
    __shared__ float smx[NSEG];
    const int t = threadIdx.x;
    if (t < NSEG) {
        sd[t] = 0.0f;
        const unsigned u = smaxu[t];
        const unsigned b = (u & 0x80000000u) ? (u ^ 0x80000000u) : ~u;
        smx[t] = __uint_as_float(b);
    }
    __syncthreads();
    const int stride = gridDim.x * blockDim.x;
    for (int i = blockIdx.x * blockDim.x + t; i < n; i += stride) {
        const int b = batch[i];
        const float e = expf(score_inout[i] - smx[b]);
        score_inout[i] = e;
        atomicAdd(&sd[b], e);
    }
    __syncthreads();
    if (t < NSEG) atomicAdd(&denom[t], sd[t]);
}

__global__ __launch_bounds__(256)
void seg_div_kernel(float* __restrict__ score_inout, const int* __restrict__ batch,
                    const float* __restrict__ denom, int n)
{
    const int stride = gridDim.x * blockDim.x;
    for (int i = blockIdx.x * blockDim.x + threadIdx.x; i < n; i += stride)
        score_inout[i] = score_inout[i] / (denom[batch[i]] + 1e-16f);
}

// ---------------------------------------------------------------------------
extern "C" void kernel_launch(void* const* d_in, const int* in_sizes, int n_in,
                              void* d_out, int out_size, void* d_ws, size_t ws_size,
                              hipStream_t stream)
{
    const float* feat  = (const float*)d_in[0];
    const int*   batch = (const int*)d_in[1];
    // d_in[2] = istrain (unused; dropout is identity at eval)
    const float* Wa = (const float*)d_in[3];
    const float* ba = (const float*)d_in[4];
    const float* Wb = (const float*)d_in[5];
    const float* bb = (const float*)d_in[6];
    const float* Wc = (const float*)d_in[7];
    const float* bc = (const float*)d_in[8];

    const int N = in_sizes[1];                 // 262144

    float* out_norm  = (float*)d_out;
    float* out_score = (float*)d_out + (size_t)N * DD;

    char* ws = (char*)d_ws;
    _Float16* Wab   = (_Float16*)ws;                         // 512 KB
    unsigned* smaxu = (unsigned*)(ws + 2 * LL * DD * 2);     // 64 u32
    float*    denom = (float*)(ws + 2 * LL * DD * 2 + 256);  // 64 f32

    prep_kernel<<<(2 * LL * DD + 255) / 256, 256, 0, stream>>>(Wa, Wb, Wab, smaxu, denom);
    // 4 waves per block, 32 rows per wave -> 128 rows per block
    fused_main<<<N / 128, 256, 0, stream>>>(feat, Wab, ba, bb, Wc, bc, out_norm, out_score);
    seg_max_kernel<<<512, 256, 0, stream>>>(out_score, batch, smaxu, N);
    seg_exp_kernel<<<512, 256, 0, stream>>>(out_score, batch, smaxu, denom, N);
    seg_div_kernel<<<512, 256, 0, stream>>>(out_score, batch, denom, N);
}